// Round 1
// baseline (398.052 us; speedup 1.0000x reference)
//
#include <hip/hip_runtime.h>

// VQ-VAE VectorQuantizer: B=32, C=D=64, H=W=64, K=512
// d_in[0]: inputs  [32,64,64,64] f32 (NCHW, C = embedding dim)
// d_in[1]: embedding [512,64] f32
// d_out: [loss(1) | out(32*64*64*64) | indices(32*4096)] all read as f32
//
// Numerics: must replicate numpy's fp32 rounding so argmin matches exactly:
//   d_k = fl(fl(x2 - 2*xe_k) + e2_k), x2/e2 via pairwise-8 sums (contract off),
//   xe via the 4-accumulator fmaf pattern (proven index-exact in prior runs).
//
// V2 (this round): the 242us vq_main was latency-stalled (VALUBusy 29%,
// HBM 2.7%) on wave-uniform scalar loads of the 128KB emb table thrashing
// the scalar cache at 2 waves/SIMD. Fix: stage emb (128KB) + e2 (2KB) in
// LDS once per block; block=512, grid=256 -> exactly 1 block/CU. Uniform
// LDS reads broadcast conflict-free and pipeline under fine-grained lgkmcnt.
// Also fused: e2 precompute into main (overlapped with staging), and loss
// finalize now sums per-block partials (plain stores, no ws init needed).

#define KCODE 512
#define EMB   64
#define HWSZ  4096          // H*W
#define BATCH 32
#define NPOS  (BATCH * HWSZ) // 131072
#define BLK   512
#define GRID  (NPOS / BLK)   // 256 blocks == 256 CUs, 1 block/CU (LDS-capped)

// numpy pairwise_sum for n=64 (unrolled-by-8 pattern), squares NOT fused.
__device__ __forceinline__ float np_sumsq64(const float* a) {
    #pragma clang fp contract(off)
    {
        float r0 = a[0] * a[0], r1 = a[1] * a[1], r2 = a[2] * a[2], r3 = a[3] * a[3];
        float r4 = a[4] * a[4], r5 = a[5] * a[5], r6 = a[6] * a[6], r7 = a[7] * a[7];
        for (int i = 8; i < 64; i += 8) {
            r0 += a[i + 0] * a[i + 0];
            r1 += a[i + 1] * a[i + 1];
            r2 += a[i + 2] * a[i + 2];
            r3 += a[i + 3] * a[i + 3];
            r4 += a[i + 4] * a[i + 4];
            r5 += a[i + 5] * a[i + 5];
            r6 += a[i + 6] * a[i + 6];
            r7 += a[i + 7] * a[i + 7];
        }
        return ((r0 + r1) + (r2 + r3)) + ((r4 + r5) + (r6 + r7));
    }
}

extern __shared__ float smem[];   // [KCODE*EMB] emb copy | [KCODE] e2

__global__ __launch_bounds__(BLK) void vq_main(
        const float* __restrict__ in,      // [32,64,4096]
        const float* __restrict__ emb,     // [512,64]
        float* __restrict__ block_loss,    // ws, [GRID] per-block partials
        float* __restrict__ out_q,         // d_out+1, [32,64,4096]
        float* __restrict__ out_idx) {     // d_out+1+NPOS*EMB, [NPOS]
    float* se  = smem;                 // emb staged, row-major [512][64]
    float* se2 = smem + KCODE * EMB;   // e2[512]

    const int tid = threadIdx.x;
    const int n   = blockIdx.x * BLK + tid;
    const int b   = n >> 12;                         // / 4096
    const int hw  = n & (HWSZ - 1);

    // Stage emb -> LDS: 8192 float4s, 16 per thread, stride-BLK coalesced.
    {
        const float4* es = (const float4*)emb;
        float4*       ed = (float4*)se;
        #pragma unroll
        for (int i = 0; i < 16; ++i) ed[tid + i * BLK] = es[tid + i * BLK];
    }
    // e2 per thread (k == tid), from GLOBAL emb so it overlaps the staging
    // (bitwise identical to computing from the LDS copy).
    se2[tid] = np_sumsq64(emb + tid * EMB);

    // Load this position's 64-dim vector (stride HWSZ between components;
    // coalesced across lanes since lanes have consecutive hw).
    const float* xp = in + (size_t)b * (EMB * HWSZ) + hw;
    float x[EMB];
    #pragma unroll
    for (int c = 0; c < EMB; ++c) x[c] = xp[(size_t)c * HWSZ];

    // x2 with numpy's exact summation pattern
    const float x2 = np_sumsq64(x);

    __syncthreads();   // emb + e2 staged

    // argmin_k fl(fl(x2 - 2*xe_k) + e2_k); k uniform -> LDS broadcast reads.
    int   best  = 0;
    float bestD = 3.4e38f;
    #pragma unroll 2
    for (int k = 0; k < KCODE; ++k) {
        const float* ek = se + k * EMB;
        float t0 = 0.f, t1 = 0.f, t2 = 0.f, t3 = 0.f;
        #pragma unroll
        for (int c = 0; c < EMB; c += 4) {
            t0 = fmaf(x[c + 0], ek[c + 0], t0);
            t1 = fmaf(x[c + 1], ek[c + 1], t1);
            t2 = fmaf(x[c + 2], ek[c + 2], t2);
            t3 = fmaf(x[c + 3], ek[c + 3], t3);
        }
        float xe = (t0 + t1) + (t2 + t3);
        // 2*xe is exact in fp32, so fma-contraction here is rounding-identical.
        float tmp = x2 - 2.0f * xe;      // fl(x2 - 2*xe): the ulp(64) quantizer
        float d   = tmp + se2[k];        // fl(tmp + e2)
        if (d < bestD) { bestD = d; best = k; }   // strict <: first min kept
    }

    // Quantized output + per-thread sum of (q - x)^2 for the loss.
    // Read the winning row from GLOBAL emb (L2-hot, 128KB): per-lane k is
    // divergent, and divergent LDS rows would be a 64-way bank conflict.
    const float4* qk = (const float4*)(emb + (size_t)best * EMB);
    float* op = out_q + (size_t)b * (EMB * HWSZ) + hw;
    float s = 0.0f;
    #pragma unroll
    for (int c4 = 0; c4 < EMB / 4; ++c4) {
        float4 v = qk[c4];
        float d0 = v.x - x[c4 * 4 + 0];
        float d1 = v.y - x[c4 * 4 + 1];
        float d2 = v.z - x[c4 * 4 + 2];
        float d3 = v.w - x[c4 * 4 + 3];
        s = fmaf(d0, d0, s); s = fmaf(d1, d1, s);
        s = fmaf(d2, d2, s); s = fmaf(d3, d3, s);
        op[(size_t)(c4 * 4 + 0) * HWSZ] = v.x;
        op[(size_t)(c4 * 4 + 1) * HWSZ] = v.y;
        op[(size_t)(c4 * 4 + 2) * HWSZ] = v.z;
        op[(size_t)(c4 * 4 + 3) * HWSZ] = v.w;
    }
    out_idx[n] = (float)best;

    // Block loss: wave shuffle -> LDS -> one plain store per block (no atomics,
    // no ws pre-zero needed: plain store overwrites poisoned workspace).
    #pragma unroll
    for (int off = 32; off > 0; off >>= 1)
        s += __shfl_down(s, off, 64);
    __shared__ float red[8];
    const int wave = tid >> 6;
    const int lane = tid & 63;
    if (lane == 0) red[wave] = s;
    __syncthreads();
    if (tid == 0) {
        float bs = ((red[0] + red[1]) + (red[2] + red[3]))
                 + ((red[4] + red[5]) + (red[6] + red[7]));
        block_loss[blockIdx.x] = bs;
    }
}

__global__ void vq_finalize(const float* __restrict__ block_loss,
                            float* __restrict__ out0) {
    // Sum 256 per-block partials deterministically; 1 block of 256 threads.
    const int tid = threadIdx.x;
    float s = block_loss[tid];
    #pragma unroll
    for (int off = 32; off > 0; off >>= 1)
        s += __shfl_down(s, off, 64);
    __shared__ float red[4];
    if ((tid & 63) == 0) red[tid >> 6] = s;
    __syncthreads();
    if (tid == 0) {
        float t = (red[0] + red[1]) + (red[2] + red[3]);
        // loss = q_latent + 0.25*e_latent = 1.25 * mean((q - x)^2)
        out0[0] = 1.25f * t * (1.0f / ((float)NPOS * (float)EMB));
    }
}

extern "C" void kernel_launch(void* const* d_in, const int* in_sizes, int n_in,
                              void* d_out, int out_size, void* d_ws, size_t ws_size,
                              hipStream_t stream) {
    const float* in  = (const float*)d_in[0];
    const float* emb = (const float*)d_in[1];
    float* ws   = (float*)d_ws;
    float* out  = (float*)d_out;

    float* out_loss = out;                              // [1]
    float* out_q    = out + 1;                          // [NPOS*EMB]
    float* out_idx  = out + 1 + (size_t)NPOS * EMB;     // [NPOS]

    constexpr size_t SHMEM = (size_t)(KCODE * EMB + KCODE) * sizeof(float); // 133120 B
    vq_main<<<GRID, BLK, SHMEM, stream>>>(in, emb, ws, out_q, out_idx);
    vq_finalize<<<1, 256, 0, stream>>>(ws, out_loss);
}

// Round 2
// 341.706 us; speedup vs baseline: 1.1649x; 1.1649x over previous
//
#include <hip/hip_runtime.h>

// VQ-VAE VectorQuantizer: B=32, C=D=64, H=W=64, K=512
// d_in[0]: inputs  [32,64,64,64] f32 (NCHW, C = embedding dim)
// d_in[1]: embedding [512,64] f32
// d_out: [loss(1) | out(32*64*64*64) | indices(32*4096)] all read as f32
//
// Numerics: must replicate numpy's fp32 rounding so argmin matches exactly:
//   d_k = fl(fl(x2 - 2*xe_k) + e2_k), x2/e2 via pairwise-8 sums (contract off),
//   xe via the 4-accumulator fmaf pattern. Here the 4 accumulators live as
//   lanes of two packed float2 accumulators (v_pk_fma_f32): each component is
//   an IEEE fp32 FMA applied in the identical order -> bitwise identical.
//
// V3 (this round): round-1's LDS staging was LDS-pipe-bound (uniform
// ds_read_b128 still writes back 1KB/wave -> ~12cyc; 8 waves share one LDS
// pipe -> 3x oversubscribed vs VALU; model 330us ~= measured 364us).
// The broadcast ek operand must come through the SCALAR path (SGPRs) so it
// rides v_fmac's free scalar port. Round-0 did that but streamed 128KB
// through the 16KB scalar cache unchunked (every iter = L2-latency miss,
// VALUBusy 29%). Fix: 1 block of 512 threads per CU (grid=256) and a
// __syncthreads()-phase-locked k-chunk loop (CHUNK=16 codes = 4KB): all 8
// waves of the CU sweep the same 4KB window together -> sL1-resident.
// Plus v_pk_fma_f32 (float2) halves the VALU instruction count.

#define KCODE 512
#define EMB   64
#define HWSZ  4096          // H*W
#define BATCH 32
#define NPOS  (BATCH * HWSZ) // 131072
#define BLK   512
#define GRID  (NPOS / BLK)   // 256 blocks -> 1 per CU
#define CHUNK 16             // codes per phase-locked window (16*256B = 4KB)

typedef float float2v __attribute__((ext_vector_type(2)));

// numpy pairwise_sum for n=64 (unrolled-by-8 pattern), squares NOT fused.
__device__ __forceinline__ float np_sumsq64(const float* a) {
    #pragma clang fp contract(off)
    {
        float r0 = a[0] * a[0], r1 = a[1] * a[1], r2 = a[2] * a[2], r3 = a[3] * a[3];
        float r4 = a[4] * a[4], r5 = a[5] * a[5], r6 = a[6] * a[6], r7 = a[7] * a[7];
        for (int i = 8; i < 64; i += 8) {
            r0 += a[i + 0] * a[i + 0];
            r1 += a[i + 1] * a[i + 1];
            r2 += a[i + 2] * a[i + 2];
            r3 += a[i + 3] * a[i + 3];
            r4 += a[i + 4] * a[i + 4];
            r5 += a[i + 5] * a[i + 5];
            r6 += a[i + 6] * a[i + 6];
            r7 += a[i + 7] * a[i + 7];
        }
        return ((r0 + r1) + (r2 + r3)) + ((r4 + r5) + (r6 + r7));
    }
}

// Same summation tree, operating on the float2-packed x (a[i] = {x[2i],x[2i+1]}).
// r0..r7 pick up exactly the same components in the same order as above.
__device__ __forceinline__ float np_sumsq64v(const float2v* a) {
    #pragma clang fp contract(off)
    {
        float r0 = a[0].x * a[0].x, r1 = a[0].y * a[0].y;
        float r2 = a[1].x * a[1].x, r3 = a[1].y * a[1].y;
        float r4 = a[2].x * a[2].x, r5 = a[2].y * a[2].y;
        float r6 = a[3].x * a[3].x, r7 = a[3].y * a[3].y;
        for (int i = 4; i < 32; i += 4) {
            r0 += a[i + 0].x * a[i + 0].x;
            r1 += a[i + 0].y * a[i + 0].y;
            r2 += a[i + 1].x * a[i + 1].x;
            r3 += a[i + 1].y * a[i + 1].y;
            r4 += a[i + 2].x * a[i + 2].x;
            r5 += a[i + 2].y * a[i + 2].y;
            r6 += a[i + 3].x * a[i + 3].x;
            r7 += a[i + 3].y * a[i + 3].y;
        }
        return ((r0 + r1) + (r2 + r3)) + ((r4 + r5) + (r6 + r7));
    }
}

// ws layout: [0..255] per-block loss partials | [256..767] e2 (numpy order)
__global__ void vq_precompute(const float* __restrict__ emb, float* __restrict__ ws) {
    int k = blockIdx.x * blockDim.x + threadIdx.x;
    if (k < KCODE) ws[256 + k] = np_sumsq64(emb + k * EMB);
}

__global__ __launch_bounds__(BLK) void vq_main(
        const float* __restrict__ in,      // [32,64,4096]
        const float* __restrict__ emb,     // [512,64]
        const float* __restrict__ e2,      // ws+256, [512]
        float* __restrict__ block_loss,    // ws+0, [GRID]
        float* __restrict__ out_q,         // d_out+1, [32,64,4096]
        float* __restrict__ out_idx) {     // d_out+1+NPOS*EMB, [NPOS]
    const int tid = threadIdx.x;
    const int n   = blockIdx.x * BLK + tid;
    const int b   = n >> 12;                         // / 4096
    const int hw  = n & (HWSZ - 1);

    // Load this position's 64-dim vector as 32 packed float2 (stride HWSZ
    // between components; coalesced across lanes: consecutive hw per lane).
    const float* xp = in + (size_t)b * (EMB * HWSZ) + hw;
    float2v xv[32];
    #pragma unroll
    for (int c2 = 0; c2 < 32; ++c2) {
        xv[c2].x = xp[(size_t)(2 * c2 + 0) * HWSZ];
        xv[c2].y = xp[(size_t)(2 * c2 + 1) * HWSZ];
    }

    // x2 with numpy's exact summation pattern
    const float x2 = np_sumsq64v(xv);

    // argmin_k fl(fl(x2 - 2*xe_k) + e2_k).
    // k is wave-uniform -> ek/e2 reads become s_loads (SGPR operands: free of
    // the VALU/LDS pipes). Chunk + barrier keeps all 8 waves of this CU in
    // the same 4KB window so the scalar cache actually holds it.
    int   best  = 0;
    float bestD = 3.4e38f;
    for (int kc = 0; kc < KCODE; kc += CHUNK) {
        __syncthreads();                 // phase-lock the CU's 8 waves
        #pragma unroll 4
        for (int k = kc; k < kc + CHUNK; ++k) {
            const float2v* ek2 = (const float2v*)(emb + k * EMB);
            float2v t01 = {0.0f, 0.0f};  // components == t0, t1
            float2v t23 = {0.0f, 0.0f};  // components == t2, t3
            #pragma unroll
            for (int c2 = 0; c2 < 32; c2 += 2) {
                t01 = __builtin_elementwise_fma(xv[c2 + 0], ek2[c2 + 0], t01);
                t23 = __builtin_elementwise_fma(xv[c2 + 1], ek2[c2 + 1], t23);
            }
            float xe = (t01.x + t01.y) + (t23.x + t23.y);   // (t0+t1)+(t2+t3)
            // 2*xe exact in fp32 -> fma-contraction here is rounding-identical.
            float tmp = x2 - 2.0f * xe;   // fl(x2 - 2*xe)
            float d   = tmp + e2[k];      // fl(tmp + e2)
            if (d < bestD) { bestD = d; best = k; }   // strict <: first min
        }
    }

    // Quantized output + per-thread sum of (q - x)^2 for the loss.
    // Winning row gathered from global emb (divergent per-lane k; L2-hot).
    const float4* qk = (const float4*)(emb + (size_t)best * EMB);
    float* op = out_q + (size_t)b * (EMB * HWSZ) + hw;
    float s = 0.0f;
    #pragma unroll
    for (int c4 = 0; c4 < EMB / 4; ++c4) {
        float4 v = qk[c4];
        float d0 = v.x - xv[2 * c4 + 0].x;
        float d1 = v.y - xv[2 * c4 + 0].y;
        float d2 = v.z - xv[2 * c4 + 1].x;
        float d3 = v.w - xv[2 * c4 + 1].y;
        s = fmaf(d0, d0, s); s = fmaf(d1, d1, s);
        s = fmaf(d2, d2, s); s = fmaf(d3, d3, s);
        op[(size_t)(4 * c4 + 0) * HWSZ] = v.x;
        op[(size_t)(4 * c4 + 1) * HWSZ] = v.y;
        op[(size_t)(4 * c4 + 2) * HWSZ] = v.z;
        op[(size_t)(4 * c4 + 3) * HWSZ] = v.w;
    }
    out_idx[n] = (float)best;

    // Block loss: wave shuffle -> LDS -> one plain store per block (no atomic,
    // plain store overwrites poisoned workspace).
    #pragma unroll
    for (int off = 32; off > 0; off >>= 1)
        s += __shfl_down(s, off, 64);
    __shared__ float red[8];
    const int wave = tid >> 6;
    const int lane = tid & 63;
    if (lane == 0) red[wave] = s;
    __syncthreads();
    if (tid == 0) {
        float bs = ((red[0] + red[1]) + (red[2] + red[3]))
                 + ((red[4] + red[5]) + (red[6] + red[7]));
        block_loss[blockIdx.x] = bs;
    }
}

__global__ void vq_finalize(const float* __restrict__ block_loss,
                            float* __restrict__ out0) {
    // Sum 256 per-block partials deterministically; 1 block of 256 threads.
    const int tid = threadIdx.x;
    float s = block_loss[tid];
    #pragma unroll
    for (int off = 32; off > 0; off >>= 1)
        s += __shfl_down(s, off, 64);
    __shared__ float red[4];
    if ((tid & 63) == 0) red[tid >> 6] = s;
    __syncthreads();
    if (tid == 0) {
        float t = (red[0] + red[1]) + (red[2] + red[3]);
        // loss = q_latent + 0.25*e_latent = 1.25 * mean((q - x)^2)
        out0[0] = 1.25f * t * (1.0f / ((float)NPOS * (float)EMB));
    }
}

extern "C" void kernel_launch(void* const* d_in, const int* in_sizes, int n_in,
                              void* d_out, int out_size, void* d_ws, size_t ws_size,
                              hipStream_t stream) {
    const float* in  = (const float*)d_in[0];
    const float* emb = (const float*)d_in[1];
    float* ws   = (float*)d_ws;
    float* out  = (float*)d_out;

    float* out_loss = out;                              // [1]
    float* out_q    = out + 1;                          // [NPOS*EMB]
    float* out_idx  = out + 1 + (size_t)NPOS * EMB;     // [NPOS]

    float* block_loss = ws;        // [256]
    float* e2         = ws + 256;  // [512]

    vq_precompute<<<2, 256, 0, stream>>>(emb, ws);
    vq_main<<<GRID, BLK, 0, stream>>>(in, emb, e2, block_loss, out_q, out_idx);
    vq_finalize<<<1, 256, 0, stream>>>(ws, out_loss);
}

// Round 3
// 298.942 us; speedup vs baseline: 1.3315x; 1.1431x over previous
//
#include <hip/hip_runtime.h>

// VQ-VAE VectorQuantizer: B=32, C=D=64, H=W=64, K=512
// d_in[0]: inputs  [32,64,64,64] f32 (NCHW, C = embedding dim)
// d_in[1]: embedding [512,64] f32
// d_out: [loss(1) | out(32*64*64*64) | indices(32*4096)] all read as f32
//
// V4: MFMA screen + exact rescore.
// Rounds 0-2 proved the exact-fp32 scan is delivery-bound on any pipe
// (broadcast ek costs >= the FMA work: LDS 64x writeback waste, scalar path
// can't pipeline in 102 SGPRs). The systolic MFMA array is the only unit
// that reuses a loaded operand ~16x in-register.
// Exactness: numpy argmin_k fl(fl(x2-2xe_k)+e2_k) is preserved by:
//   screen  s~_k = e2_k + sum((-2x)*(e)) via bf16 hi/lo split MFMA
//           (error <= ~7e-5 worst case incl. numpy's own rounding window)
//   emit    all k with s~_k <= min_k s~ + EPS (EPS=1e-3, 4x margin, CAP=6,
//           overflow -> exact full-scan fallback)
//   rescore candidates with the round-0-proven exact fmaf path, pick
//           lexicographic (u,k) min == numpy first-min.

#define KCODE 512
#define EMB   64
#define HWSZ  4096
#define NPOS  131072
#define EPSW  1e-3f
#define CAP   6

typedef short  short8  __attribute__((ext_vector_type(8)));
typedef float  float4v __attribute__((ext_vector_type(4)));

// ws float layout:
//   [0..511]     per-block loss partials (512 main blocks)
//   [512..1023]  e2 (numpy rounding, by code)
//   [1024..]     B-fragments: short8[32][2][2][64]  (128 KB)

// ---------- numpy-exact helpers ----------
__device__ __forceinline__ float np_sumsq64(const float* a) {
    #pragma clang fp contract(off)
    {
        float r0 = a[0] * a[0], r1 = a[1] * a[1], r2 = a[2] * a[2], r3 = a[3] * a[3];
        float r4 = a[4] * a[4], r5 = a[5] * a[5], r6 = a[6] * a[6], r7 = a[7] * a[7];
        for (int i = 8; i < 64; i += 8) {
            r0 += a[i + 0] * a[i + 0];
            r1 += a[i + 1] * a[i + 1];
            r2 += a[i + 2] * a[i + 2];
            r3 += a[i + 3] * a[i + 3];
            r4 += a[i + 4] * a[i + 4];
            r5 += a[i + 5] * a[i + 5];
            r6 += a[i + 6] * a[i + 6];
            r7 += a[i + 7] * a[i + 7];
        }
        return ((r0 + r1) + (r2 + r3)) + ((r4 + r5) + (r6 + r7));
    }
}

// exact numpy distance core: u = fl(fl(x2 - 2*xe) + e2k)  (proven in round 0)
__device__ __forceinline__ float exact_u(const float* x, float x2,
                                         const float* ek, float e2k) {
    float t0 = 0.f, t1 = 0.f, t2 = 0.f, t3 = 0.f;
    #pragma unroll
    for (int c = 0; c < EMB; c += 4) {
        t0 = fmaf(x[c + 0], ek[c + 0], t0);
        t1 = fmaf(x[c + 1], ek[c + 1], t1);
        t2 = fmaf(x[c + 2], ek[c + 2], t2);
        t3 = fmaf(x[c + 3], ek[c + 3], t3);
    }
    float xe  = (t0 + t1) + (t2 + t3);
    float tmp = x2 - 2.0f * xe;     // 2*xe exact -> contraction rounding-identical
    return tmp + e2k;
}

__device__ __forceinline__ unsigned short bf16rne(float f) {
    unsigned u = __float_as_uint(f);
    unsigned r = (u + 0x7FFFu + ((u >> 16) & 1u)) >> 16;   // round-nearest-even
    return (unsigned short)r;
}
__device__ __forceinline__ float bf16tof(unsigned short h) {
    return __uint_as_float((unsigned)h << 16);
}

// ---------- prep kernels ----------
__global__ void vq_e2(const float* __restrict__ emb, float* __restrict__ ws) {
    int k = blockIdx.x * blockDim.x + threadIdx.x;
    if (k < KCODE) ws[512 + k] = np_sumsq64(emb + k * EMB);
}

// Build bf16 hi/lo B-fragments, laid out exactly as the sweep loads them:
// frag index f = t*256 + c*128 + hl*64 + lane; element j holds
// e[code = 16t + (lane&15)][d = 32c + (lane>>4)*8 + j].
__global__ void vq_bfrag(const float* __restrict__ emb, short8* __restrict__ bfrag) {
    int f = blockIdx.x * blockDim.x + threadIdx.x;   // 0..4095 over (t,c,lane)
    int l = f & 63;
    int c = (f >> 6) & 1;
    int t = f >> 7;            // 0..31
    int code  = t * 16 + (l & 15);
    int dbase = 32 * c + ((l >> 4) & 3) * 8;
    const float* e = emb + code * EMB + dbase;
    short8 h, lo;
    #pragma unroll
    for (int j = 0; j < 8; ++j) {
        float v = e[j];
        unsigned short hb = bf16rne(v);
        float hf = bf16tof(hb);
        unsigned short lb = bf16rne(v - hf);
        h[j]  = (short)hb;
        lo[j] = (short)lb;
    }
    bfrag[t * 256 + c * 128 + 0 * 64 + l] = h;
    bfrag[t * 256 + c * 128 + 1 * 64 + l] = lo;
}

// ---------- main kernel ----------
__global__ __launch_bounds__(256) void vq_main(
        const float*  __restrict__ in,        // [32,64,4096]
        const float*  __restrict__ emb,       // [512,64]
        const float*  __restrict__ e2np,      // ws+512
        const short8* __restrict__ bfrag,     // ws+1024
        float* __restrict__ loss_part,        // ws+0, [512]
        float* __restrict__ out_q,            // d_out+1
        float* __restrict__ out_idx) {        // d_out+1+NPOS*EMB
    __shared__ int            cnt[256];
    __shared__ unsigned short ks[256][CAP];
    __shared__ float          red[4];

    const int tid  = threadIdx.x;
    const int wave = tid >> 6;
    const int lane = tid & 63;
    const int lg   = lane >> 4;    // k-group (A/B) / row-group (C)
    const int lc   = lane & 15;    // A-row / B-col / C-col

    cnt[tid] = 0;

    // ---- pack A-fragments: 4 position-tiles x 2 dim-chunks, hi/lo of (-2x)
    // A element j of lane: row = lane&15 (position), k = (lane>>4)*8 + j (dim).
    const int blockPos = blockIdx.x * 256;
    const int wavePos  = blockPos + wave * 64;
    short8 fH[4][2], fL[4][2];
    #pragma unroll
    for (int pt = 0; pt < 4; ++pt) {
        int pos = wavePos + pt * 16 + lc;
        int b   = pos >> 12;
        int hw  = pos & (HWSZ - 1);
        const float* xb = in + ((size_t)b << 18) + hw;   // in[b][0][hw]
        #pragma unroll
        for (int c = 0; c < 2; ++c) {
            short8 h, lo;
            #pragma unroll
            for (int j = 0; j < 8; ++j) {
                int d = 32 * c + lg * 8 + j;
                float g = -2.0f * xb[(size_t)d << 12];   // exact scale
                unsigned short hb = bf16rne(g);
                float hf = bf16tof(hb);
                unsigned short lb = bf16rne(g - hf);
                h[j]  = (short)hb;
                lo[j] = (short)lb;
            }
            fH[pt][c] = h;
            fL[pt][c] = lo;
        }
    }
    __syncthreads();   // cnt zeroed before any emission

    // ---- sweep 1: per-position running min of s~ ----
    float4v m[4];
    #pragma unroll
    for (int pt = 0; pt < 4; ++pt) m[pt] = (float4v){3.4e38f, 3.4e38f, 3.4e38f, 3.4e38f};

    for (int t = 0; t < 32; ++t) {
        const short8 eh0 = bfrag[t * 256 +   0 + lane];
        const short8 el0 = bfrag[t * 256 +  64 + lane];
        const short8 eh1 = bfrag[t * 256 + 128 + lane];
        const short8 el1 = bfrag[t * 256 + 192 + lane];
        const float e2v  = e2np[t * 16 + lc];
        #pragma unroll
        for (int pt = 0; pt < 4; ++pt) {
            float4v a = (float4v){e2v, e2v, e2v, e2v};
            a = __builtin_amdgcn_mfma_f32_16x16x32_bf16(fH[pt][0], eh0, a, 0, 0, 0);
            a = __builtin_amdgcn_mfma_f32_16x16x32_bf16(fH[pt][1], eh1, a, 0, 0, 0);
            a = __builtin_amdgcn_mfma_f32_16x16x32_bf16(fH[pt][0], el0, a, 0, 0, 0);
            a = __builtin_amdgcn_mfma_f32_16x16x32_bf16(fH[pt][1], el1, a, 0, 0, 0);
            a = __builtin_amdgcn_mfma_f32_16x16x32_bf16(fL[pt][0], eh0, a, 0, 0, 0);
            a = __builtin_amdgcn_mfma_f32_16x16x32_bf16(fL[pt][1], eh1, a, 0, 0, 0);
            #pragma unroll
            for (int r = 0; r < 4; ++r) m[pt][r] = fminf(m[pt][r], a[r]);
        }
    }

    // cross-lane min over the 16-lane col group (masks <16 stay in-group)
    #pragma unroll
    for (int pt = 0; pt < 4; ++pt) {
        #pragma unroll
        for (int r = 0; r < 4; ++r) {
            float v = m[pt][r];
            v = fminf(v, __shfl_xor(v, 1, 64));
            v = fminf(v, __shfl_xor(v, 2, 64));
            v = fminf(v, __shfl_xor(v, 4, 64));
            v = fminf(v, __shfl_xor(v, 8, 64));
            m[pt][r] = v + EPSW;     // threshold
        }
    }

    // ---- sweep 2: bitwise-identical recompute, emit candidates ----
    for (int t = 0; t < 32; ++t) {
        const short8 eh0 = bfrag[t * 256 +   0 + lane];
        const short8 el0 = bfrag[t * 256 +  64 + lane];
        const short8 eh1 = bfrag[t * 256 + 128 + lane];
        const short8 el1 = bfrag[t * 256 + 192 + lane];
        const float e2v  = e2np[t * 16 + lc];
        #pragma unroll
        for (int pt = 0; pt < 4; ++pt) {
            float4v a = (float4v){e2v, e2v, e2v, e2v};
            a = __builtin_amdgcn_mfma_f32_16x16x32_bf16(fH[pt][0], eh0, a, 0, 0, 0);
            a = __builtin_amdgcn_mfma_f32_16x16x32_bf16(fH[pt][1], eh1, a, 0, 0, 0);
            a = __builtin_amdgcn_mfma_f32_16x16x32_bf16(fH[pt][0], el0, a, 0, 0, 0);
            a = __builtin_amdgcn_mfma_f32_16x16x32_bf16(fH[pt][1], el1, a, 0, 0, 0);
            a = __builtin_amdgcn_mfma_f32_16x16x32_bf16(fL[pt][0], eh0, a, 0, 0, 0);
            a = __builtin_amdgcn_mfma_f32_16x16x32_bf16(fL[pt][1], eh1, a, 0, 0, 0);
            #pragma unroll
            for (int r = 0; r < 4; ++r) {
                if (a[r] <= m[pt][r]) {      // s~ <= min + EPS
                    int p = wave * 64 + pt * 16 + lg * 4 + r;   // C-row position
                    int slot = atomicAdd(&cnt[p], 1);
                    if (slot < CAP) ks[p][slot] = (unsigned short)(t * 16 + lc);
                }
            }
        }
    }
    __syncthreads();   // candidate lists complete

    // ---- exact rescore + outputs: thread <-> position ----
    const int n  = blockPos + tid;
    const int b  = n >> 12;
    const int hw = n & (HWSZ - 1);
    const float* xp = in + ((size_t)b << 18) + hw;
    float x[EMB];
    #pragma unroll
    for (int c = 0; c < EMB; ++c) x[c] = xp[(size_t)c << 12];
    const float x2 = np_sumsq64(x);

    int count = cnt[tid];
    int   bk = 0;
    float bu = 3.4e38f;
    if (count >= 1 && count <= CAP) {
        bk = 0x7fffffff;
        for (int i = 0; i < count; ++i) {
            int k  = ks[tid][i];
            float u = exact_u(x, x2, emb + k * EMB, e2np[k]);
            if (u < bu || (u == bu && k < bk)) { bu = u; bk = k; }
        }
    } else {
        // overflow (or impossible 0): exact full scan, first-min semantics
        for (int k = 0; k < KCODE; ++k) {
            float u = exact_u(x, x2, emb + k * EMB, e2np[k]);
            if (u < bu) { bu = u; bk = k; }
        }
    }

    // quantized output + per-thread (q-x)^2 partial
    const float4* qk = (const float4*)(emb + (size_t)bk * EMB);
    float* op = out_q + ((size_t)b << 18) + hw;
    float s = 0.0f;
    #pragma unroll
    for (int c4 = 0; c4 < EMB / 4; ++c4) {
        float4 v = qk[c4];
        float d0 = v.x - x[c4 * 4 + 0];
        float d1 = v.y - x[c4 * 4 + 1];
        float d2 = v.z - x[c4 * 4 + 2];
        float d3 = v.w - x[c4 * 4 + 3];
        s = fmaf(d0, d0, s); s = fmaf(d1, d1, s);
        s = fmaf(d2, d2, s); s = fmaf(d3, d3, s);
        op[(size_t)(c4 * 4 + 0) << 12] = v.x;
        op[(size_t)(c4 * 4 + 1) << 12] = v.y;
        op[(size_t)(c4 * 4 + 2) << 12] = v.z;
        op[(size_t)(c4 * 4 + 3) << 12] = v.w;
    }
    out_idx[n] = (float)bk;

    #pragma unroll
    for (int off = 32; off > 0; off >>= 1)
        s += __shfl_down(s, off, 64);
    if (lane == 0) red[wave] = s;
    __syncthreads();
    if (tid == 0)
        loss_part[blockIdx.x] = (red[0] + red[1]) + (red[2] + red[3]);
}

__global__ void vq_finalize(const float* __restrict__ loss_part,
                            float* __restrict__ out0) {
    const int tid = threadIdx.x;   // 512 threads
    float s = loss_part[tid];
    #pragma unroll
    for (int off = 32; off > 0; off >>= 1)
        s += __shfl_down(s, off, 64);
    __shared__ float red[8];
    if ((tid & 63) == 0) red[tid >> 6] = s;
    __syncthreads();
    if (tid == 0) {
        float t = ((red[0] + red[1]) + (red[2] + red[3]))
                + ((red[4] + red[5]) + (red[6] + red[7]));
        out0[0] = 1.25f * t * (1.0f / ((float)NPOS * (float)EMB));
    }
}

extern "C" void kernel_launch(void* const* d_in, const int* in_sizes, int n_in,
                              void* d_out, int out_size, void* d_ws, size_t ws_size,
                              hipStream_t stream) {
    const float* in  = (const float*)d_in[0];
    const float* emb = (const float*)d_in[1];
    float* ws  = (float*)d_ws;
    float* out = (float*)d_out;

    float*  out_loss = out;
    float*  out_q    = out + 1;
    float*  out_idx  = out + 1 + (size_t)NPOS * EMB;
    float*  loss_p   = ws;                      // [512]
    float*  e2np     = ws + 512;                // [512]
    short8* bfrag    = (short8*)(ws + 1024);    // 128 KB

    vq_e2<<<2, 256, 0, stream>>>(emb, ws);
    vq_bfrag<<<16, 256, 0, stream>>>(emb, bfrag);
    vq_main<<<512, 256, 0, stream>>>(in, emb, e2np, bfrag, loss_p, out_q, out_idx);
    vq_finalize<<<1, 512, 0, stream>>>(loss_p, out_loss);
}